// Round 4
// baseline (122.259 us; speedup 1.0000x reference)
//
#include <hip/hip_runtime.h>

#define NN 10000    // nodes
#define NE 25000    // edges
#define DF 128      // features
#define HS 32768    // hash slots (pow2), load factor ~0.76 worst case
#define HMASK (HS - 1)

__device__ __forceinline__ unsigned hslot(int key) {
    return ((unsigned)key * 2654435761u >> 15) & HMASK;
}

// ---------------------------------------------------------------------------
// K1: new_x[e] = ((x[u]+x[v])*0.5 + edge_attr[e])*0.5 (32 thr/edge, float4)
//     + zero cntNode / hash table / global cursor (reuses the big grid).
// ---------------------------------------------------------------------------
__global__ void k_newx_zero(const float* __restrict__ x, const float* __restrict__ ea,
                            const int* __restrict__ c0, const int* __restrict__ c1,
                            float* __restrict__ out, int* __restrict__ cntNode,
                            int* __restrict__ hashK, int* __restrict__ hashC,
                            int* __restrict__ gCursor) {
    int tid = blockIdx.x * blockDim.x + threadIdx.x;
    if (tid < NN) cntNode[tid] = 0;
    if (tid < HS) { hashK[tid] = -1; hashC[tid] = 0; }
    if (tid == 0) *gCursor = 0;
    if (tid >= NE * 32) return;
    int e = tid >> 5, q = tid & 31;
    int u = c0[e], v = c1[e];
    float4 a = ((const float4*)(x + (size_t)u * DF))[q];
    float4 b = ((const float4*)(x + (size_t)v * DF))[q];
    float4 c = ((const float4*)(ea + (size_t)e * DF))[q];
    float4 r;
    r.x = ((a.x + b.x) * 0.5f + c.x) * 0.5f;
    r.y = ((a.y + b.y) * 0.5f + c.y) * 0.5f;
    r.z = ((a.z + b.z) * 0.5f + c.z) * 0.5f;
    r.w = ((a.w + b.w) * 0.5f + c.w) * 0.5f;
    ((float4*)(out + (size_t)e * DF))[q] = r;
}

// ---------------------------------------------------------------------------
// K2: histogram of c0 + hash-count of (u,v) pairs (for duplicate-reverse test)
// ---------------------------------------------------------------------------
__global__ void k_count(const int* __restrict__ c0, const int* __restrict__ c1,
                        int* __restrict__ cntNode,
                        int* __restrict__ hashK, int* __restrict__ hashC) {
    int j = blockIdx.x * blockDim.x + threadIdx.x;
    if (j >= NE) return;
    int u = c0[j], v = c1[j];
    atomicAdd(&cntNode[u], 1);
    int key = u * NN + v;
    unsigned h = hslot(key);
    while (true) {
        int prev = atomicCAS(&hashK[h], -1, key);
        if (prev == -1 || prev == key) { atomicAdd(&hashC[h], 1); break; }
        h = (h + 1) & HMASK;
    }
}

__device__ __forceinline__ int hlookup(const int* __restrict__ hashK,
                                       const int* __restrict__ hashC, int key) {
    unsigned h = hslot(key);
    while (true) {
        int k = hashK[h];
        if (k == key) return hashC[h];
        if (k == -1) return 0;
        h = (h + 1) & HMASK;
    }
}

// ---------------------------------------------------------------------------
// K3: two independent jobs after K2:
//   tid <  NN       : bucket-space allocation via one global cursor (no scan!)
//   tid in [NN,NN+NE): cnt_edge[i] = deg(c1[i]) - #edges(c1[i] -> c0[i])
// ---------------------------------------------------------------------------
__global__ void k_alloc_cnt(const int* __restrict__ c0, const int* __restrict__ c1,
                            const int* __restrict__ cntNode,
                            const int* __restrict__ hashK, const int* __restrict__ hashC,
                            int* __restrict__ bOff, int* __restrict__ cursor,
                            int* __restrict__ gCursor, int* __restrict__ cntEdge) {
    int tid = blockIdx.x * blockDim.x + threadIdx.x;
    if (tid < NN) {
        int c = cntNode[tid];
        int off = (c > 0) ? atomicAdd(gCursor, c) : 0;
        bOff[tid] = off;
        cursor[tid] = off;
    } else if (tid < NN + NE) {
        int i = tid - NN;
        int u = c0[i], v = c1[i];
        cntEdge[i] = cntNode[v] - hlookup(hashK, hashC, v * NN + u);
    }
}

// ---------------------------------------------------------------------------
// K4: 26 blocks x 1024. Blocks 0..24: atomic-cursor bucket fill.
//     Block 25: single-block exclusive scan of cntEdge -> rowStart[0..NE].
// ---------------------------------------------------------------------------
__global__ __launch_bounds__(1024) void k_fill_scan(const int* __restrict__ c0,
                                                    int* __restrict__ cursor,
                                                    int* __restrict__ bEdges,
                                                    const int* __restrict__ cntEdge,
                                                    int* __restrict__ rowStart) {
    int b = blockIdx.x, t = threadIdx.x;
    if (b < 25) {
        int j = b * 1024 + t;
        if (j < NE) {
            int p = atomicAdd(&cursor[c0[j]], 1);
            bEdges[p] = j;
        }
        return;
    }
    // block 25: exclusive scan over NE elements
    __shared__ int part[1024];
    const int C = (NE + 1023) >> 10;
    int lo = t * C; if (lo > NE) lo = NE;
    int hi = lo + C; if (hi > NE) hi = NE;
    int s = 0;
    for (int i = lo; i < hi; ++i) s += cntEdge[i];
    part[t] = s;
    __syncthreads();
    for (int off = 1; off < 1024; off <<= 1) {
        int add = (t >= off) ? part[t - off] : 0;
        __syncthreads();
        part[t] += add;
        __syncthreads();
    }
    int run = (t == 0) ? 0 : part[t - 1];
    for (int i = lo; i < hi; ++i) { rowStart[i] = run; run += cntEdge[i]; }
    if (t == 0) rowStart[NE] = part[1023];
}

// ---------------------------------------------------------------------------
// K5: one wave per edge i. attr rows for row i are identical copies of
// new_x[c1[i]]; rows/cols restored to ascending-j order via rank-by-value
// (buckets are tiny, avg 2.5).
// ---------------------------------------------------------------------------
__global__ void k_emit(const float* __restrict__ newx,
                       const int* __restrict__ c0, const int* __restrict__ c1,
                       const int* __restrict__ cntNode, const int* __restrict__ bOff,
                       const int* __restrict__ bEdges, const int* __restrict__ rowStart,
                       float* __restrict__ outRows, float* __restrict__ outCols,
                       float* __restrict__ outAttr) {
    int gtid = blockIdx.x * blockDim.x + threadIdx.x;
    int i = gtid >> 6, lane = gtid & 63;
    if (i >= NE) return;
    int base = rowStart[i];
    int cnt  = rowStart[i + 1] - base;
    if (cnt == 0) return;
    int u = c0[i], v = c1[i];
    // attr copies (float2/lane = 512B per wave-store)
    float2 val = ((const float2*)(newx + (size_t)v * DF))[lane];
    for (int t = 0; t < cnt; ++t)
        ((float2*)(outAttr + (size_t)(base + t) * DF))[lane] = val;
    // rows/cols: rank-by-value within bucket
    int bs = bOff[v], B = cntNode[v];
    for (int p = lane; p < B; p += 64) {
        int jp = bEdges[bs + p];
        if (c1[jp] == u) continue;
        int rank = 0;
        for (int q = 0; q < B; ++q) {
            int jq = bEdges[bs + q];
            rank += (c1[jq] != u && jq < jp) ? 1 : 0;
        }
        outRows[base + rank] = (float)i;
        outCols[base + rank] = (float)jp;
    }
}

// ---------------------------------------------------------------------------

extern "C" void kernel_launch(void* const* d_in, const int* in_sizes, int n_in,
                              void* d_out, int out_size, void* d_ws, size_t ws_size,
                              hipStream_t stream) {
    const float* x  = (const float*)d_in[0];
    const float* ea = (const float*)d_in[1];
    const int*   ei = (const int*)d_in[2];
    const int* c0 = ei;        // edge_index[0]
    const int* c1 = ei + NE;   // edge_index[1]

    float* out = (float*)d_out;
    int E_lg = (out_size - NE * DF) / (DF + 2);
    if (E_lg < 0) E_lg = 0;

    float* out_newx = out;                      // NE*DF
    float* out_rows = out + (size_t)NE * DF;    // E_lg
    float* out_cols = out_rows + E_lg;          // E_lg
    float* out_attr = out_cols + E_lg;          // E_lg*DF

    int* ws       = (int*)d_ws;
    int* cntNode  = ws;                         // NN
    int* bOff     = cntNode + NN;               // NN
    int* cursor   = bOff + NN;                  // NN
    int* bEdges   = cursor + NN;                // NE
    int* cntEdge  = bEdges + NE;                // NE
    int* rowStart = cntEdge + NE;               // NE+1
    int* hashK    = rowStart + NE + 1;          // HS
    int* hashC    = hashK + HS;                 // HS
    int* gCursor  = hashC + HS;                 // 1

    k_newx_zero<<<(NE * 32 + 255) / 256, 256, 0, stream>>>(x, ea, c0, c1, out_newx,
                                                           cntNode, hashK, hashC, gCursor);
    k_count<<<(NE + 255) / 256, 256, 0, stream>>>(c0, c1, cntNode, hashK, hashC);
    k_alloc_cnt<<<(NN + NE + 255) / 256, 256, 0, stream>>>(c0, c1, cntNode, hashK, hashC,
                                                           bOff, cursor, gCursor, cntEdge);
    k_fill_scan<<<26, 1024, 0, stream>>>(c0, cursor, bEdges, cntEdge, rowStart);
    k_emit<<<(NE * 64 + 255) / 256, 256, 0, stream>>>(out_newx, c0, c1, cntNode, bOff,
                                                      bEdges, rowStart,
                                                      out_rows, out_cols, out_attr);
}

// Round 5
// 81.081 us; speedup vs baseline: 1.5079x; 1.5079x over previous
//
#include <hip/hip_runtime.h>

#define NN 10000    // nodes
#define NE 25000    // edges
#define DF 128      // features

// ---------------------------------------------------------------------------
// K1: new_x[e] = ((x[u]+x[v])*0.5 + edge_attr[e])*0.5 (32 thr/edge, float4)
//     + init head[] = -1 (first NN threads).
// ---------------------------------------------------------------------------
__global__ void k_newx_zero(const float* __restrict__ x, const float* __restrict__ ea,
                            const int* __restrict__ c0, const int* __restrict__ c1,
                            float* __restrict__ out, int* __restrict__ head) {
    int tid = blockIdx.x * blockDim.x + threadIdx.x;
    if (tid < NN) head[tid] = -1;
    if (tid >= NE * 32) return;
    int e = tid >> 5, q = tid & 31;
    int u = c0[e], v = c1[e];
    float4 a = ((const float4*)(x + (size_t)u * DF))[q];
    float4 b = ((const float4*)(x + (size_t)v * DF))[q];
    float4 c = ((const float4*)(ea + (size_t)e * DF))[q];
    float4 r;
    r.x = ((a.x + b.x) * 0.5f + c.x) * 0.5f;
    r.y = ((a.y + b.y) * 0.5f + c.y) * 0.5f;
    r.z = ((a.z + b.z) * 0.5f + c.z) * 0.5f;
    r.w = ((a.w + b.w) * 0.5f + c.w) * 0.5f;
    ((float4*)(out + (size_t)e * DF))[q] = r;
}

// ---------------------------------------------------------------------------
// K2: build per-node linked lists in ONE pass (no count/scan/fill).
// ---------------------------------------------------------------------------
__global__ void k_link(const int* __restrict__ c0,
                       int* __restrict__ head, int* __restrict__ nxt) {
    int j = blockIdx.x * blockDim.x + threadIdx.x;
    if (j >= NE) return;
    nxt[j] = atomicExch(&head[c0[j]], j);
}

// ---------------------------------------------------------------------------
// K3: cnt_edge[i] = #(j in list(c1[i]) with c1[j] != c0[i]) — order-free.
// ---------------------------------------------------------------------------
__global__ void k_cnt(const int* __restrict__ c0, const int* __restrict__ c1,
                      const int* __restrict__ head, const int* __restrict__ nxt,
                      int* __restrict__ cntEdge) {
    int i = blockIdx.x * blockDim.x + threadIdx.x;
    if (i >= NE) return;
    int u = c0[i], v = c1[i];
    int c = 0;
    for (int j = head[v]; j != -1; j = nxt[j])
        if (c1[j] != u) ++c;
    cntEdge[i] = c;
}

// ---------------------------------------------------------------------------
// K4: single-block exclusive scan: rowStart[0..NE], rowStart[NE] = total.
// ---------------------------------------------------------------------------
__global__ __launch_bounds__(1024) void k_scan(const int* __restrict__ in,
                                               int* __restrict__ out) {
    __shared__ int part[1024];
    int t = threadIdx.x;
    const int C = (NE + 1023) >> 10;
    int lo = t * C; if (lo > NE) lo = NE;
    int hi = lo + C; if (hi > NE) hi = NE;
    int s = 0;
    for (int i = lo; i < hi; ++i) s += in[i];
    part[t] = s;
    __syncthreads();
    for (int off = 1; off < 1024; off <<= 1) {
        int add = (t >= off) ? part[t - off] : 0;
        __syncthreads();
        part[t] += add;
        __syncthreads();
    }
    int run = (t == 0) ? 0 : part[t - 1];
    for (int i = lo; i < hi; ++i) { out[i] = run; run += in[i]; }
    if (t == 0) out[NE] = part[1023];
}

// ---------------------------------------------------------------------------
// K5: one wave per edge i.
//  - attr rows for row i: cnt identical copies of new_x[c1[i]] (float2/lane).
//  - rows/cols: lane l owns the l-th list element; rank-by-value restores
//    ascending-j order (all list walks are wave-broadcast loads).
// ---------------------------------------------------------------------------
__global__ void k_emit(const float* __restrict__ newx,
                       const int* __restrict__ c0, const int* __restrict__ c1,
                       const int* __restrict__ head, const int* __restrict__ nxt,
                       const int* __restrict__ rowStart,
                       float* __restrict__ outRows, float* __restrict__ outCols,
                       float* __restrict__ outAttr) {
    int gtid = blockIdx.x * blockDim.x + threadIdx.x;
    int i = gtid >> 6, lane = gtid & 63;
    if (i >= NE) return;
    int base = rowStart[i];
    int cnt  = rowStart[i + 1] - base;
    if (cnt == 0) return;
    int u = c0[i], v = c1[i];
    // attr: cnt identical copies of new_x[v]
    float2 val = ((const float2*)(newx + (size_t)v * DF))[lane];
    for (int t = 0; t < cnt; ++t)
        ((float2*)(outAttr + (size_t)(base + t) * DF))[lane] = val;
    // rows/cols: walk list; lane l takes elements at positions l, l+64, ...
    int pos = 0;
    for (int j = head[v]; j != -1; j = nxt[j], ++pos) {
        if ((pos & 63) != lane) continue;
        if (c1[j] == u) continue;
        int rank = 0;
        for (int j2 = head[v]; j2 != -1; j2 = nxt[j2])
            rank += (c1[j2] != u && j2 < j) ? 1 : 0;
        outRows[base + rank] = (float)i;
        outCols[base + rank] = (float)j;
    }
}

// ---------------------------------------------------------------------------

extern "C" void kernel_launch(void* const* d_in, const int* in_sizes, int n_in,
                              void* d_out, int out_size, void* d_ws, size_t ws_size,
                              hipStream_t stream) {
    const float* x  = (const float*)d_in[0];
    const float* ea = (const float*)d_in[1];
    const int*   ei = (const int*)d_in[2];
    const int* c0 = ei;        // edge_index[0]
    const int* c1 = ei + NE;   // edge_index[1]

    float* out = (float*)d_out;
    int E_lg = (out_size - NE * DF) / (DF + 2);
    if (E_lg < 0) E_lg = 0;

    float* out_newx = out;                      // NE*DF
    float* out_rows = out + (size_t)NE * DF;    // E_lg
    float* out_cols = out_rows + E_lg;          // E_lg
    float* out_attr = out_cols + E_lg;          // E_lg*DF

    int* ws       = (int*)d_ws;
    int* head     = ws;                         // NN
    int* nxt      = head + NN;                  // NE
    int* cntEdge  = nxt + NE;                   // NE
    int* rowStart = cntEdge + NE;               // NE+1

    k_newx_zero<<<(NE * 32 + 255) / 256, 256, 0, stream>>>(x, ea, c0, c1, out_newx, head);
    k_link<<<(NE + 255) / 256, 256, 0, stream>>>(c0, head, nxt);
    k_cnt<<<(NE + 255) / 256, 256, 0, stream>>>(c0, c1, head, nxt, cntEdge);
    k_scan<<<1, 1024, 0, stream>>>(cntEdge, rowStart);
    k_emit<<<(NE * 64 + 255) / 256, 256, 0, stream>>>(out_newx, c0, c1, head, nxt,
                                                      rowStart, out_rows, out_cols, out_attr);
}

// Round 6
// 38.620 us; speedup vs baseline: 3.1657x; 2.0995x over previous
//
#include <hip/hip_runtime.h>

#define NN 10000    // nodes
#define NE 25000    // edges
#define DF 128      // features
#define SB 256      // scan block size
#define NBLK ((NE + SB - 1) / SB)   // 98 scan blocks

// ---------------------------------------------------------------------------
// K1: new_x[e] = ((x[u]+x[v])*0.5 + edge_attr[e])*0.5 (32 thr/edge, float4)
//     + init head[] = -1 and lookback flags = 0.
// ---------------------------------------------------------------------------
__global__ void k_newx_init(const float* __restrict__ x, const float* __restrict__ ea,
                            const int* __restrict__ c0, const int* __restrict__ c1,
                            float* __restrict__ out, int* __restrict__ head,
                            int* __restrict__ gFlag) {
    int tid = blockIdx.x * blockDim.x + threadIdx.x;
    if (tid < NN) head[tid] = -1;
    if (tid < NBLK) gFlag[tid] = 0;
    if (tid >= NE * 32) return;
    int e = tid >> 5, q = tid & 31;
    int u = c0[e], v = c1[e];
    float4 a = ((const float4*)(x + (size_t)u * DF))[q];
    float4 b = ((const float4*)(x + (size_t)v * DF))[q];
    float4 c = ((const float4*)(ea + (size_t)e * DF))[q];
    float4 r;
    r.x = ((a.x + b.x) * 0.5f + c.x) * 0.5f;
    r.y = ((a.y + b.y) * 0.5f + c.y) * 0.5f;
    r.z = ((a.z + b.z) * 0.5f + c.z) * 0.5f;
    r.w = ((a.w + b.w) * 0.5f + c.w) * 0.5f;
    ((float4*)(out + (size_t)e * DF))[q] = r;
}

// ---------------------------------------------------------------------------
// K2: per-node linked lists in one pass.
// ---------------------------------------------------------------------------
__global__ void k_link(const int* __restrict__ c0,
                       int* __restrict__ head, int* __restrict__ nxt) {
    int j = blockIdx.x * blockDim.x + threadIdx.x;
    if (j >= NE) return;
    nxt[j] = atomicExch(&head[c0[j]], j);
}

// ---------------------------------------------------------------------------
// K3: fused cnt_edge + global exclusive scan -> rowStart[0..NE].
// 98 blocks x 256. Per-thread list-walk count, LDS inclusive scan, then
// publish (blockSum+1) in gFlag[b] (0 = not ready); thread t<b spins on
// predecessor t's flag, LDS-reduce -> block base. All 98 blocks co-resident
// -> no deadlock regardless of dispatch order. Deterministic (sum of fixed
// per-edge counts).
// ---------------------------------------------------------------------------
__global__ __launch_bounds__(SB) void k_cnt_scan(const int* __restrict__ c0,
                                                 const int* __restrict__ c1,
                                                 const int* __restrict__ head,
                                                 const int* __restrict__ nxt,
                                                 int* __restrict__ gFlag,
                                                 int* __restrict__ rowStart) {
    __shared__ int sc[SB];
    __shared__ int sr[SB];
    int b = blockIdx.x, t = threadIdx.x;
    int i = b * SB + t;
    int cnt = 0;
    if (i < NE) {
        int u = c0[i], v = c1[i];
        for (int j = head[v]; j != -1; j = nxt[j])
            if (c1[j] != u) ++cnt;
    }
    sc[t] = cnt;
    __syncthreads();
    for (int off = 1; off < SB; off <<= 1) {
        int add = (t >= off) ? sc[t - off] : 0;
        __syncthreads();
        sc[t] += add;
        __syncthreads();
    }
    int blockSum = sc[SB - 1];
    if (t == 0) atomicExch(&gFlag[b], blockSum + 1);   // publish (device scope)
    // parallel lookback: thread t waits on predecessor block t
    int val = 0;
    if (t < b) {
        int v2;
        do { v2 = atomicAdd(&gFlag[t], 0); } while (v2 == 0);
        val = v2 - 1;
    }
    sr[t] = val;
    __syncthreads();
    for (int off = SB / 2; off > 0; off >>= 1) {
        if (t < off) sr[t] += sr[t + off];
        __syncthreads();
    }
    int base = sr[0];
    if (i < NE) rowStart[i] = base + sc[t] - cnt;      // exclusive
    if (b == NBLK - 1 && t == 0) rowStart[NE] = base + blockSum;
}

// ---------------------------------------------------------------------------
// K4: one wave per edge i (i is wave-uniform).
//  - single list walk: lane l owns element l; rank-by-value via shfl loop.
//  - attr: wave writes TWO identical rows per store (float4/lane, 1KB/inst).
//  - slow-path only if bucket > 64 (practically never for this input).
// ---------------------------------------------------------------------------
__global__ void k_emit(const float* __restrict__ newx,
                       const int* __restrict__ c0, const int* __restrict__ c1,
                       const int* __restrict__ head, const int* __restrict__ nxt,
                       const int* __restrict__ rowStart,
                       float* __restrict__ outRows, float* __restrict__ outCols,
                       float* __restrict__ outAttr) {
    int gtid = blockIdx.x * blockDim.x + threadIdx.x;
    int i = gtid >> 6, lane = gtid & 63;
    if (i >= NE) return;
    int base = rowStart[i];
    int cnt  = rowStart[i + 1] - base;
    if (cnt == 0) return;
    int u = c0[i], v = c1[i];

    // walk list once; lane l records element l
    int myj = -1, B = 0;
    for (int j = head[v]; j != -1; j = nxt[j], ++B)
        if (B == lane) myj = j;

    if (B <= 64) {
        int myc1 = (myj >= 0) ? c1[myj] : -1;
        bool keep = (myj >= 0) && (myc1 != u);
        int rank = 0;
        for (int q = 0; q < B; ++q) {
            int jq = __shfl(myj, q);
            int cq = __shfl(myc1, q);
            if (cq != u && jq < myj) ++rank;
        }
        if (keep) {
            outRows[base + rank] = (float)i;
            outCols[base + rank] = (float)myj;
        }
    } else {
        // generic fallback: rank via full re-walk
        int pos = 0;
        for (int j = head[v]; j != -1; j = nxt[j], ++pos) {
            if ((pos & 63) != lane) continue;
            if (c1[j] == u) continue;
            int rank = 0;
            for (int j2 = head[v]; j2 != -1; j2 = nxt[j2])
                rank += (c1[j2] != u && j2 < j) ? 1 : 0;
            outRows[base + rank] = (float)i;
            outCols[base + rank] = (float)j;
        }
    }

    // attr: cnt identical copies of new_x[v]; 2 rows per store instruction
    float4 val = ((const float4*)(newx + (size_t)v * DF))[lane & 31];
    for (int tt = (lane >> 5); tt < cnt; tt += 2)
        ((float4*)(outAttr + (size_t)(base + tt) * DF))[lane & 31] = val;
}

// ---------------------------------------------------------------------------

extern "C" void kernel_launch(void* const* d_in, const int* in_sizes, int n_in,
                              void* d_out, int out_size, void* d_ws, size_t ws_size,
                              hipStream_t stream) {
    const float* x  = (const float*)d_in[0];
    const float* ea = (const float*)d_in[1];
    const int*   ei = (const int*)d_in[2];
    const int* c0 = ei;        // edge_index[0]
    const int* c1 = ei + NE;   // edge_index[1]

    float* out = (float*)d_out;
    int E_lg = (out_size - NE * DF) / (DF + 2);
    if (E_lg < 0) E_lg = 0;

    float* out_newx = out;                      // NE*DF
    float* out_rows = out + (size_t)NE * DF;    // E_lg
    float* out_cols = out_rows + E_lg;          // E_lg
    float* out_attr = out_cols + E_lg;          // E_lg*DF

    int* ws       = (int*)d_ws;
    int* head     = ws;                         // NN
    int* nxt      = head + NN;                  // NE
    int* rowStart = nxt + NE;                   // NE+1
    int* gFlag    = rowStart + NE + 1;          // NBLK

    k_newx_init<<<(NE * 32 + 255) / 256, 256, 0, stream>>>(x, ea, c0, c1, out_newx,
                                                           head, gFlag);
    k_link<<<(NE + 255) / 256, 256, 0, stream>>>(c0, head, nxt);
    k_cnt_scan<<<NBLK, SB, 0, stream>>>(c0, c1, head, nxt, gFlag, rowStart);
    k_emit<<<(NE * 64 + 255) / 256, 256, 0, stream>>>(out_newx, c0, c1, head, nxt,
                                                      rowStart, out_rows, out_cols, out_attr);
}